// Round 1
// baseline (638.392 us; speedup 1.0000x reference)
//
#include <hip/hip_runtime.h>

#define H 1024
#define S 1024
#define B 32
#define K2 2048  // 2*H

typedef unsigned short u16;
typedef __attribute__((ext_vector_type(8))) short short8;     // 8 bf16 (4 VGPRs) — MFMA A/B frag
typedef __attribute__((ext_vector_type(8))) unsigned short u16x8;
typedef __attribute__((ext_vector_type(4))) float floatx4;    // MFMA C/D frag

__device__ __forceinline__ u16 f2bf(float f) {
  unsigned u = __float_as_uint(f);
  u += 0x7FFFu + ((u >> 16) & 1u);   // round-to-nearest-even to bf16
  return (u16)(u >> 16);
}

// encoder_states (S,B,2H) fp32 -> enc_bf16 (B,S,2H) bf16 (transpose for dense per-batch A)
__global__ void conv_enc_k(const float* __restrict__ src, u16* __restrict__ dst) {
  const int blk = blockIdx.x;           // = s*B + b
  const int s = blk >> 5, b = blk & 31;
  const int t = threadIdx.x * 8;
  const float* sp = src + (size_t)blk * K2 + t;
  u16* dp = dst + ((size_t)b * S + s) * K2 + t;
  floatx4 x = *(const floatx4*)sp;
  floatx4 y = *(const floatx4*)(sp + 4);
  u16x8 o;
  o[0] = f2bf(x[0]); o[1] = f2bf(x[1]); o[2] = f2bf(x[2]); o[3] = f2bf(x[3]);
  o[4] = f2bf(y[0]); o[5] = f2bf(y[1]); o[6] = f2bf(y[2]); o[7] = f2bf(y[3]);
  *(u16x8*)dp = o;
}

// W_attn (H,3H) fp32 -> W_e bf16 (H,2H)
__global__ void conv_we_k(const float* __restrict__ W, u16* __restrict__ dst) {
  const int h = blockIdx.x;
  const int t = threadIdx.x * 8;
  const float* sp = W + (size_t)h * 3072 + H + t;
  u16* dp = dst + (size_t)h * K2 + t;
  floatx4 x = *(const floatx4*)sp;
  floatx4 y = *(const floatx4*)(sp + 4);
  u16x8 o;
  o[0] = f2bf(x[0]); o[1] = f2bf(x[1]); o[2] = f2bf(x[2]); o[3] = f2bf(x[3]);
  o[4] = f2bf(y[0]); o[5] = f2bf(y[1]); o[6] = f2bf(y[2]); o[7] = f2bf(y[3]);
  *(u16x8*)dp = o;
}

// h_proj[b,h] = hidden[b,:] . W_attn[h, 0:H] + b_attn[h]   (fp32 exact path)
// one wave per h; loop b inside so the W row is read once per wave
__global__ void hproj_k(const float* __restrict__ hidden, const float* __restrict__ W,
                        const float* __restrict__ b_attn, float* __restrict__ hp) {
  const int lane = threadIdx.x & 63;
  const int h = (blockIdx.x * blockDim.x + threadIdx.x) >> 6;
  float wr[16];
#pragma unroll
  for (int i = 0; i < 16; i++) wr[i] = W[(size_t)h * 3072 + lane + i * 64];
  for (int b = 0; b < B; b++) {
    float d = 0.f;
#pragma unroll
    for (int i = 0; i < 16; i++) d = fmaf(wr[i], hidden[b * H + lane + i * 64], d);
#pragma unroll
    for (int off = 32; off; off >>= 1) d += __shfl_xor(d, off);
    if (lane == 0) hp[b * H + h] = d + b_attn[h];
  }
}

// Fused GEMM: e_proj tile (128 s x 128 h) over K=2048, epilogue tanh(+h_proj)*v_w
// reduced over local h -> atomicAdd into attn[b,s]. e_proj never hits memory.
#define BM 128
#define BN 128
#define BK 32
#define LDT 40  // padded LDS row stride (bf16 elems): 20 dwords -> 2-way max on frag reads (free)

__global__ __launch_bounds__(256) void gemm_fused_k(
    const u16* __restrict__ A,   // (B,S,2H) bf16
    const u16* __restrict__ Bw,  // (H,2H) bf16
    const float* __restrict__ hp, const float* __restrict__ vw,
    float* __restrict__ attn) {
  __shared__ __align__(16) u16 sA[BM * LDT];
  __shared__ __align__(16) u16 sB[BN * LDT];
  const int tid = threadIdx.x;
  const int bid = blockIdx.x;
  // id = ntile*256 + b*8 + mtile: the 8 ntile-variants of one (b,mtile) share id%8 -> same XCD (A reuse)
  const int ntile = bid >> 8;
  const int b = (bid & 255) >> 3;
  const int mtile = bid & 7;
  const int s0 = mtile * BM;
  const int h0 = ntile * BN;

  const int srow = tid >> 2;        // 0..63 (two passes cover 128 rows)
  const int seg = (tid & 3) * 8;    // 8-elem (16B) segment in k
  const u16* aG = A + ((size_t)(b * S + s0 + srow)) * K2 + seg;
  const u16* bG = Bw + ((size_t)(h0 + srow)) * K2 + seg;

  const int lane = tid & 63;
  const int wv = tid >> 6;
  const int wm = (wv >> 1) * 64;
  const int wn = (wv & 1) * 64;
  const int fr = lane & 15;         // A row / B col within 16-frag
  const int kk = (lane >> 4) * 8;   // k sub-block

  floatx4 acc[4][4];
#pragma unroll
  for (int i = 0; i < 4; i++)
#pragma unroll
    for (int j = 0; j < 4; j++) acc[i][j] = (floatx4){0.f, 0.f, 0.f, 0.f};

  for (int k0 = 0; k0 < K2; k0 += BK) {
    __syncthreads();
#pragma unroll
    for (int p = 0; p < 2; p++) {
      *(floatx4*)&sA[(srow + p * 64) * LDT + seg] =
          *(const floatx4*)(aG + (size_t)p * 64 * K2 + k0);
      *(floatx4*)&sB[(srow + p * 64) * LDT + seg] =
          *(const floatx4*)(bG + (size_t)p * 64 * K2 + k0);
    }
    __syncthreads();
    short8 af[4], bf[4];
#pragma unroll
    for (int mf = 0; mf < 4; mf++)
      af[mf] = *(const short8*)&sA[(wm + mf * 16 + fr) * LDT + kk];
#pragma unroll
    for (int nf = 0; nf < 4; nf++)
      bf[nf] = *(const short8*)&sB[(wn + nf * 16 + fr) * LDT + kk];
#pragma unroll
    for (int mf = 0; mf < 4; mf++)
#pragma unroll
      for (int nf = 0; nf < 4; nf++)
        acc[mf][nf] =
            __builtin_amdgcn_mfma_f32_16x16x32_bf16(af[mf], bf[nf], acc[mf][nf], 0, 0, 0);
  }

  // Epilogue. C/D map: col = lane&15, row = (lane>>4)*4 + reg  [verified m89/m91]
  const int col = fr;
  const int rgrp = lane >> 4;
  float hv[4], vv[4];
#pragma unroll
  for (int nf = 0; nf < 4; nf++) {
    const int h = h0 + wn + nf * 16 + col;
    hv[nf] = hp[b * H + h];
    vv[nf] = vw[h];
  }
#pragma unroll
  for (int mf = 0; mf < 4; mf++) {
#pragma unroll
    for (int r = 0; r < 4; r++) {
      float part = 0.f;
#pragma unroll
      for (int nf = 0; nf < 4; nf++) part += tanhf(acc[mf][nf][r] + hv[nf]) * vv[nf];
      part += __shfl_xor(part, 1);
      part += __shfl_xor(part, 2);
      part += __shfl_xor(part, 4);
      part += __shfl_xor(part, 8);   // sum over the 16 col-lanes; preserves rgrp
      if (col == 0)
        atomicAdd(&attn[b * S + s0 + wm + mf * 16 + rgrp * 4 + r], part);
    }
  }
}

__global__ void softmax_k(const float* __restrict__ attn, float* __restrict__ out) {
  __shared__ float red[8];
  const int b = blockIdx.x;
  const int tid = threadIdx.x;
  const float* row = attn + b * S;
  float v[4];
#pragma unroll
  for (int i = 0; i < 4; i++) v[i] = row[tid + i * 256];
  float m = fmaxf(fmaxf(v[0], v[1]), fmaxf(v[2], v[3]));
#pragma unroll
  for (int off = 32; off; off >>= 1) m = fmaxf(m, __shfl_xor(m, off));
  if ((tid & 63) == 0) red[tid >> 6] = m;
  __syncthreads();
  m = fmaxf(fmaxf(red[0], red[1]), fmaxf(red[2], red[3]));
  float e[4], sum = 0.f;
#pragma unroll
  for (int i = 0; i < 4; i++) { e[i] = __expf(v[i] - m); sum += e[i]; }
#pragma unroll
  for (int off = 32; off; off >>= 1) sum += __shfl_xor(sum, off);
  __syncthreads();
  if ((tid & 63) == 0) red[4 + (tid >> 6)] = sum;
  __syncthreads();
  sum = red[4] + red[5] + red[6] + red[7];
  const float inv = 1.0f / sum;
#pragma unroll
  for (int i = 0; i < 4; i++) out[b * S + tid + i * 256] = e[i] * inv;
}

extern "C" void kernel_launch(void* const* d_in, const int* in_sizes, int n_in,
                              void* d_out, int out_size, void* d_ws, size_t ws_size,
                              hipStream_t stream) {
  const float* enc    = (const float*)d_in[0];  // (S,B,2H)
  const float* hidden = (const float*)d_in[1];  // (B,H)
  // d_in[2] = cell — unused by the reference
  const float* W_attn = (const float*)d_in[3];  // (H,3H)
  const float* b_attn = (const float*)d_in[4];  // (H)
  const float* v_w    = (const float*)d_in[5];  // (H)
  float* out = (float*)d_out;                   // (B,S)

  char* ws = (char*)d_ws;
  float* attn = (float*)ws;                                  // 128 KiB
  float* hp   = (float*)(ws + 131072);                       // 128 KiB
  u16* Web    = (u16*)(ws + 262144);                         // 4 MiB
  u16* encb   = (u16*)(ws + 262144 + (size_t)H * K2 * 2);    // 128 MiB

  hipMemsetAsync(attn, 0, B * S * sizeof(float), stream);    // ws is 0xAA-poisoned each call
  conv_enc_k<<<S * B, 256, 0, stream>>>(enc, encb);
  conv_we_k<<<H, 256, 0, stream>>>(W_attn, Web);
  hproj_k<<<256, 256, 0, stream>>>(hidden, W_attn, b_attn, hp);
  gemm_fused_k<<<2048, 256, 0, stream>>>(encb, Web, hp, v_w, attn);
  softmax_k<<<B, 256, 0, stream>>>(attn, out);
}

// Round 2
// 611.557 us; speedup vs baseline: 1.0439x; 1.0439x over previous
//
#include <hip/hip_runtime.h>

#define H 1024
#define S 1024
#define B 32
#define K2 2048  // 2*H

typedef unsigned short u16;
typedef __attribute__((ext_vector_type(8))) short short8;     // 8 bf16 (4 VGPRs) — MFMA A/B frag
typedef __attribute__((ext_vector_type(8))) unsigned short u16x8;
typedef __attribute__((ext_vector_type(4))) float floatx4;    // MFMA C/D frag

__device__ __forceinline__ u16 f2bf(float f) {
  unsigned u = __float_as_uint(f);
  u += 0x7FFFu + ((u >> 16) & 1u);   // round-to-nearest-even to bf16
  return (u16)(u >> 16);
}

// async global->LDS, 16B per lane; LDS dest = wave-uniform base + lane*16
__device__ __forceinline__ void gld_lds16(const u16* g, u16* l) {
  __builtin_amdgcn_global_load_lds(
      (const __attribute__((address_space(1))) unsigned int*)g,
      (__attribute__((address_space(3))) unsigned int*)l, 16, 0, 0);
}

// encoder_states (S,B,2H) fp32 -> enc_bf16 (B,S,2H) bf16.
// b-major blocks: each block writes 16KB contiguous; reads 8KB chunks @256KB stride.
__global__ void conv_enc_k(const float* __restrict__ src, u16* __restrict__ dst) {
  const int b = blockIdx.x >> 8;        // 0..31
  const int sc = blockIdx.x & 255;      // s0 = sc*4
  const int t = threadIdx.x * 8;
#pragma unroll
  for (int i = 0; i < 4; i++) {
    const int s = sc * 4 + i;
    const float* sp = src + ((size_t)s * B + b) * K2 + t;
    u16* dp = dst + ((size_t)b * S + s) * K2 + t;
    floatx4 x = *(const floatx4*)sp;
    floatx4 y = *(const floatx4*)(sp + 4);
    u16x8 o;
    o[0] = f2bf(x[0]); o[1] = f2bf(x[1]); o[2] = f2bf(x[2]); o[3] = f2bf(x[3]);
    o[4] = f2bf(y[0]); o[5] = f2bf(y[1]); o[6] = f2bf(y[2]); o[7] = f2bf(y[3]);
    *(u16x8*)dp = o;
  }
}

// W_attn (H,3H) fp32 -> W_e bf16 (H,2H)
__global__ void conv_we_k(const float* __restrict__ W, u16* __restrict__ dst) {
  const int h = blockIdx.x;
  const int t = threadIdx.x * 8;
  const float* sp = W + (size_t)h * 3072 + H + t;
  u16* dp = dst + (size_t)h * K2 + t;
  floatx4 x = *(const floatx4*)sp;
  floatx4 y = *(const floatx4*)(sp + 4);
  u16x8 o;
  o[0] = f2bf(x[0]); o[1] = f2bf(x[1]); o[2] = f2bf(x[2]); o[3] = f2bf(x[3]);
  o[4] = f2bf(y[0]); o[5] = f2bf(y[1]); o[6] = f2bf(y[2]); o[7] = f2bf(y[3]);
  *(u16x8*)dp = o;
}

// h_proj[b,h] = hidden[b,:] . W_attn[h, 0:H] + b_attn[h]   (fp32 exact path)
__global__ void hproj_k(const float* __restrict__ hidden, const float* __restrict__ W,
                        const float* __restrict__ b_attn, float* __restrict__ hp) {
  const int lane = threadIdx.x & 63;
  const int h = (blockIdx.x * blockDim.x + threadIdx.x) >> 6;
  float wr[16];
#pragma unroll
  for (int i = 0; i < 16; i++) wr[i] = W[(size_t)h * 3072 + lane + i * 64];
  for (int b = 0; b < B; b++) {
    float d = 0.f;
#pragma unroll
    for (int i = 0; i < 16; i++) d = fmaf(wr[i], hidden[b * H + lane + i * 64], d);
#pragma unroll
    for (int off = 32; off; off >>= 1) d += __shfl_xor(d, off);
    if (lane == 0) hp[b * H + h] = d + b_attn[h];
  }
}

// Fused GEMM (m97 structure): 128x128 tile, BK=32, global_load_lds width-16 staging,
// XOR-swizzled k-segments to break ds_read_b128 bank aliasing.
// Epilogue: tanh(+h_proj)*v_w, reduce local h, atomicAdd into attn[b,s].
#define BM 128
#define BN 128
#define BK 32   // bf16 elems -> 64B LDS rows, unpadded (required by global_load_lds)

__global__ __launch_bounds__(256) void gemm_fused_k(
    const u16* __restrict__ A,   // (B,S,2H) bf16
    const u16* __restrict__ Bw,  // (H,2H) bf16
    const float* __restrict__ hp, const float* __restrict__ vw,
    float* __restrict__ attn) {
  __shared__ __align__(16) u16 sA[BM * BK];
  __shared__ __align__(16) u16 sB[BN * BK];
  const int tid = threadIdx.x;
  const int bid = blockIdx.x;
  // id = ntile*256 + b*8 + mtile: 8 ntile-variants of one (b,mtile) share id%8 -> same XCD
  const int ntile = bid >> 8;
  const int b = (bid & 255) >> 3;
  const int mtile = bid & 7;
  const int s0 = mtile * BM;
  const int h0 = ntile * BN;

  const int lane = tid & 63;
  const int wv = tid >> 6;
  const int wm = (wv >> 1) * 64;
  const int wn = (wv & 1) * 64;
  const int fr = lane & 15;         // frag row (A s-row / B h-row)
  const int kgrp = lane >> 4;       // k sub-block 0..3 (16B granule)

  // staging lane mapping: 16 rows x 4 segs per 1KB wave-load
  const int lr = lane >> 2;         // 0..15 row within chunk
  const int sg = lane & 3;          // 16B segment slot

  const u16* Ab = A + (size_t)(b * S + s0) * K2;
  const u16* Bb = Bw + (size_t)h0 * K2;

  floatx4 acc[4][4];
#pragma unroll
  for (int i = 0; i < 4; i++)
#pragma unroll
    for (int j = 0; j < 4; j++) acc[i][j] = (floatx4){0.f, 0.f, 0.f, 0.f};

  for (int k0 = 0; k0 < K2; k0 += BK) {
    __syncthreads();   // prev frag reads done before overwrite
#pragma unroll
    for (int p = 0; p < 2; p++) {
      const int rA = wv * 32 + p * 16 + lr;   // tile row this lane stages
      // LDS slot (row, sg) receives global segment (sg ^ (row&3))
      gld_lds16(Ab + (size_t)rA * K2 + k0 + (size_t)((sg ^ (rA & 3)) * 8),
                &sA[(wv * 32 + p * 16) * BK]);
      gld_lds16(Bb + (size_t)rA * K2 + k0 + (size_t)((sg ^ (rA & 3)) * 8),
                &sB[(wv * 32 + p * 16) * BK]);
    }
    __syncthreads();   // drains vmcnt(0): staged data visible

    short8 af[4], bf[4];
#pragma unroll
    for (int mf = 0; mf < 4; mf++) {
      const int row = wm + mf * 16 + fr;
      af[mf] = *(const short8*)&sA[row * BK + (kgrp ^ (row & 3)) * 8];
    }
#pragma unroll
    for (int nf = 0; nf < 4; nf++) {
      const int row = wn + nf * 16 + fr;
      bf[nf] = *(const short8*)&sB[row * BK + (kgrp ^ (row & 3)) * 8];
    }
#pragma unroll
    for (int mf = 0; mf < 4; mf++)
#pragma unroll
      for (int nf = 0; nf < 4; nf++)
        acc[mf][nf] =
            __builtin_amdgcn_mfma_f32_16x16x32_bf16(af[mf], bf[nf], acc[mf][nf], 0, 0, 0);
  }

  // Epilogue. C/D map: col = lane&15, row = (lane>>4)*4 + reg  [verified round 1]
  const int col = fr;
  const int rgrp = lane >> 4;
  float hv[4], vv[4];
#pragma unroll
  for (int nf = 0; nf < 4; nf++) {
    const int h = h0 + wn + nf * 16 + col;
    hv[nf] = hp[b * H + h];
    vv[nf] = vw[h];
  }
#pragma unroll
  for (int mf = 0; mf < 4; mf++) {
#pragma unroll
    for (int r = 0; r < 4; r++) {
      float part = 0.f;
#pragma unroll
      for (int nf = 0; nf < 4; nf++) part += tanhf(acc[mf][nf][r] + hv[nf]) * vv[nf];
      part += __shfl_xor(part, 1);
      part += __shfl_xor(part, 2);
      part += __shfl_xor(part, 4);
      part += __shfl_xor(part, 8);   // sum over the 16 col-lanes; preserves rgrp
      if (col == 0)
        atomicAdd(&attn[b * S + s0 + wm + mf * 16 + rgrp * 4 + r], part);
    }
  }
}

__global__ void softmax_k(const float* __restrict__ attn, float* __restrict__ out) {
  __shared__ float red[8];
  const int b = blockIdx.x;
  const int tid = threadIdx.x;
  const float* row = attn + b * S;
  float v[4];
#pragma unroll
  for (int i = 0; i < 4; i++) v[i] = row[tid + i * 256];
  float m = fmaxf(fmaxf(v[0], v[1]), fmaxf(v[2], v[3]));
#pragma unroll
  for (int off = 32; off; off >>= 1) m = fmaxf(m, __shfl_xor(m, off));
  if ((tid & 63) == 0) red[tid >> 6] = m;
  __syncthreads();
  m = fmaxf(fmaxf(red[0], red[1]), fmaxf(red[2], red[3]));
  float e[4], sum = 0.f;
#pragma unroll
  for (int i = 0; i < 4; i++) { e[i] = __expf(v[i] - m); sum += e[i]; }
#pragma unroll
  for (int off = 32; off; off >>= 1) sum += __shfl_xor(sum, off);
  __syncthreads();
  if ((tid & 63) == 0) red[4 + (tid >> 6)] = sum;
  __syncthreads();
  sum = red[4] + red[5] + red[6] + red[7];
  const float inv = 1.0f / sum;
#pragma unroll
  for (int i = 0; i < 4; i++) out[b * S + tid + i * 256] = e[i] * inv;
}

extern "C" void kernel_launch(void* const* d_in, const int* in_sizes, int n_in,
                              void* d_out, int out_size, void* d_ws, size_t ws_size,
                              hipStream_t stream) {
  const float* enc    = (const float*)d_in[0];  // (S,B,2H)
  const float* hidden = (const float*)d_in[1];  // (B,H)
  // d_in[2] = cell — unused by the reference
  const float* W_attn = (const float*)d_in[3];  // (H,3H)
  const float* b_attn = (const float*)d_in[4];  // (H)
  const float* v_w    = (const float*)d_in[5];  // (H)
  float* out = (float*)d_out;                   // (B,S)

  char* ws = (char*)d_ws;
  float* attn = (float*)ws;                                  // 128 KiB
  float* hp   = (float*)(ws + 131072);                       // 128 KiB
  u16* Web    = (u16*)(ws + 262144);                         // 4 MiB
  u16* encb   = (u16*)(ws + 262144 + (size_t)H * K2 * 2);    // 128 MiB

  hipMemsetAsync(attn, 0, B * S * sizeof(float), stream);    // ws is 0xAA-poisoned each call
  conv_enc_k<<<B * 256, 256, 0, stream>>>(enc, encb);
  conv_we_k<<<H, 256, 0, stream>>>(W_attn, Web);
  hproj_k<<<256, 256, 0, stream>>>(hidden, W_attn, b_attn, hp);
  gemm_fused_k<<<2048, 256, 0, stream>>>(encb, Web, hp, v_w, attn);
  softmax_k<<<B, 256, 0, stream>>>(attn, out);
}

// Round 3
// 607.778 us; speedup vs baseline: 1.0504x; 1.0062x over previous
//
#include <hip/hip_runtime.h>
#include <hip/hip_bf16.h>

#define H 1024
#define S 1024
#define B 32
#define K2 2048  // 2*H

typedef unsigned short u16;
typedef __attribute__((ext_vector_type(8))) short short8;     // 8 bf16 (4 VGPRs) — MFMA A/B frag
typedef __attribute__((ext_vector_type(8))) unsigned short u16x8;
typedef __attribute__((ext_vector_type(4))) float floatx4;    // MFMA C/D frag

__device__ __forceinline__ u16 f2bf(float f) {
  unsigned u = __float_as_uint(f);
  u += 0x7FFFu + ((u >> 16) & 1u);   // RNE to bf16
  return (u16)(u >> 16);
}

// async global->LDS, 16B per lane; global addr is PER-LANE, LDS dest = base + lane*16
__device__ __forceinline__ void gld_lds16(const void* g, void* l) {
  __builtin_amdgcn_global_load_lds(
      (const __attribute__((address_space(1))) unsigned int*)g,
      (__attribute__((address_space(3))) unsigned int*)l, 16, 0, 0);
}

// packed fp32 pair -> bf16 pair (v_cvt_pk_bf16_f32 on gfx950)
__device__ __forceinline__ unsigned cvt_pk(float lo, float hi) {
  __hip_bfloat162 h = __float22bfloat162_rn(float2{lo, hi});
  return *(unsigned*)&h;   // low16 = lo, high16 = hi
}

__device__ __forceinline__ short8 mk_frag(floatx4 lo, floatx4 hi) {
  union { unsigned u[4]; short8 s; } r;
  r.u[0] = cvt_pk(lo[0], lo[1]);
  r.u[1] = cvt_pk(lo[2], lo[3]);
  r.u[2] = cvt_pk(hi[0], hi[1]);
  r.u[3] = cvt_pk(hi[2], hi[3]);
  return r.s;
}

// W_attn (H,3H) fp32 -> W_e bf16 (H,2H)
__global__ void conv_we_k(const float* __restrict__ W, u16* __restrict__ dst) {
  const int h = blockIdx.x;
  const int t = threadIdx.x * 8;
  const float* sp = W + (size_t)h * 3072 + H + t;
  u16* dp = dst + (size_t)h * K2 + t;
  floatx4 x = *(const floatx4*)sp;
  floatx4 y = *(const floatx4*)(sp + 4);
  u16x8 o;
  o[0] = f2bf(x[0]); o[1] = f2bf(x[1]); o[2] = f2bf(x[2]); o[3] = f2bf(x[3]);
  o[4] = f2bf(y[0]); o[5] = f2bf(y[1]); o[6] = f2bf(y[2]); o[7] = f2bf(y[3]);
  *(u16x8*)dp = o;
}

// h_proj[b,h] = hidden[b,:] . W_attn[h, 0:H] + b_attn[h]   (fp32 exact path)
__global__ void hproj_k(const float* __restrict__ hidden, const float* __restrict__ W,
                        const float* __restrict__ b_attn, float* __restrict__ hp) {
  const int lane = threadIdx.x & 63;
  const int h = (blockIdx.x * blockDim.x + threadIdx.x) >> 6;
  float wr[16];
#pragma unroll
  for (int i = 0; i < 16; i++) wr[i] = W[(size_t)h * 3072 + lane + i * 64];
  for (int b = 0; b < B; b++) {
    float d = 0.f;
#pragma unroll
    for (int i = 0; i < 16; i++) d = fmaf(wr[i], hidden[b * H + lane + i * 64], d);
#pragma unroll
    for (int off = 32; off; off >>= 1) d += __shfl_xor(d, off);
    if (lane == 0) hp[b * H + h] = d + b_attn[h];
  }
}

// Fused conv+GEMM: A staged as fp32 DIRECTLY from enc (S,B,2H) via per-lane-gather
// global_load_lds; fp32->bf16 conversion in the frag-read path (packed cvt).
// Swizzles sized to the row-stride bank folding: A rows 128B (xor row&7),
// B rows 64B (xor (row>>1)&3) -> max 2-way on all ds_read_b128 (free).
#define BM 128
#define BN 128
#define BK 32

__global__ __launch_bounds__(256) void gemm_fused_k(
    const float* __restrict__ enc,  // (S,B,2H) fp32
    const u16* __restrict__ Bw,     // (H,2H) bf16
    const float* __restrict__ hp, const float* __restrict__ vw,
    float* __restrict__ attn) {
  __shared__ __align__(16) float sA[BM * 32];  // 16 KB; row = 8 segs x 4 floats, seg-swizzled
  __shared__ __align__(16) u16 sB[BN * BK];    // 8 KB; row = 4 segs x 8 bf16, seg-swizzled
  const int tid = threadIdx.x;
  const int bid = blockIdx.x;
  // id = ntile*256 + b*8 + mtile: id%8 = mtile -> each XCD owns one 32MB enc slice (LLC-resident)
  const int ntile = bid >> 8;
  const int b = (bid & 255) >> 3;
  const int mtile = bid & 7;
  const int s0 = mtile * BM;
  const int h0 = ntile * BN;

  const int lane = tid & 63;
  const int wv = tid >> 6;
  const int wm = (wv >> 1) * 64;
  const int wn = (wv & 1) * 64;
  const int fr = lane & 15;         // frag row (A s-row / B h-row)
  const int kgrp = lane >> 4;       // k sub-block 0..3 (8 elems)

  const int lr8 = lane >> 3, sg8 = lane & 7;  // A staging: 8 rows x 8 segs per call
  const int lr4 = lane >> 2, sg4 = lane & 3;  // B staging: 16 rows x 4 segs per call

  floatx4 acc[4][4];
#pragma unroll
  for (int i = 0; i < 4; i++)
#pragma unroll
    for (int j = 0; j < 4; j++) acc[i][j] = (floatx4){0.f, 0.f, 0.f, 0.f};

  for (int k0 = 0; k0 < K2; k0 += BK) {
    __syncthreads();   // prev frag reads done before overwrite
    // A: fp32 gather from (S,B,2H); 4 calls cover this wave's 32 rows
#pragma unroll
    for (int p = 0; p < 4; p++) {
      const int r = wv * 32 + p * 8 + lr8;                 // tile row
      gld_lds16(enc + ((size_t)(s0 + r) * B + b) * K2 + k0 + ((sg8 ^ (r & 7)) << 2),
                (char*)sA + (wv * 32 + p * 8) * 128);
    }
    // B: bf16; 2 calls cover this wave's 32 rows
#pragma unroll
    for (int p = 0; p < 2; p++) {
      const int r = wv * 32 + p * 16 + lr4;
      gld_lds16(Bw + (size_t)(h0 + r) * K2 + k0 + ((sg4 ^ ((r >> 1) & 3)) << 3),
                (char*)sB + (wv * 32 + p * 16) * 64);
    }
    __syncthreads();   // drains vmcnt(0): staged data visible

    short8 af[4], bf[4];
#pragma unroll
    for (int mf = 0; mf < 4; mf++) {
      const int R = wm + mf * 16 + fr;
      const int f7 = R & 7;
      floatx4 lo = *(const floatx4*)&sA[R * 32 + ((((kgrp << 1)) ^ f7) << 2)];
      floatx4 hi = *(const floatx4*)&sA[R * 32 + ((((kgrp << 1) | 1) ^ f7) << 2)];
      af[mf] = mk_frag(lo, hi);
    }
#pragma unroll
    for (int nf = 0; nf < 4; nf++) {
      const int R = wn + nf * 16 + fr;
      bf[nf] = *(const short8*)&sB[R * BK + ((kgrp ^ ((R >> 1) & 3)) << 3)];
    }
#pragma unroll
    for (int mf = 0; mf < 4; mf++)
#pragma unroll
      for (int nf = 0; nf < 4; nf++)
        acc[mf][nf] =
            __builtin_amdgcn_mfma_f32_16x16x32_bf16(af[mf], bf[nf], acc[mf][nf], 0, 0, 0);
  }

  // Epilogue. C/D map: col = lane&15, row = (lane>>4)*4 + reg  [verified round 1]
  const int col = fr;
  const int rgrp = lane >> 4;
  float hv[4], vv[4];
#pragma unroll
  for (int nf = 0; nf < 4; nf++) {
    const int h = h0 + wn + nf * 16 + col;
    hv[nf] = hp[b * H + h];
    vv[nf] = vw[h];
  }
#pragma unroll
  for (int mf = 0; mf < 4; mf++) {
#pragma unroll
    for (int r = 0; r < 4; r++) {
      float part = 0.f;
#pragma unroll
      for (int nf = 0; nf < 4; nf++) part += tanhf(acc[mf][nf][r] + hv[nf]) * vv[nf];
      part += __shfl_xor(part, 1);
      part += __shfl_xor(part, 2);
      part += __shfl_xor(part, 4);
      part += __shfl_xor(part, 8);   // sum over the 16 col-lanes; preserves rgrp
      if (col == 0)
        atomicAdd(&attn[b * S + s0 + wm + mf * 16 + rgrp * 4 + r], part);
    }
  }
}

__global__ void softmax_k(const float* __restrict__ attn, float* __restrict__ out) {
  __shared__ float red[8];
  const int b = blockIdx.x;
  const int tid = threadIdx.x;
  const float* row = attn + b * S;
  float v[4];
#pragma unroll
  for (int i = 0; i < 4; i++) v[i] = row[tid + i * 256];
  float m = fmaxf(fmaxf(v[0], v[1]), fmaxf(v[2], v[3]));
#pragma unroll
  for (int off = 32; off; off >>= 1) m = fmaxf(m, __shfl_xor(m, off));
  if ((tid & 63) == 0) red[tid >> 6] = m;
  __syncthreads();
  m = fmaxf(fmaxf(red[0], red[1]), fmaxf(red[2], red[3]));
  float e[4], sum = 0.f;
#pragma unroll
  for (int i = 0; i < 4; i++) { e[i] = __expf(v[i] - m); sum += e[i]; }
#pragma unroll
  for (int off = 32; off; off >>= 1) sum += __shfl_xor(sum, off);
  __syncthreads();
  if ((tid & 63) == 0) red[4 + (tid >> 6)] = sum;
  __syncthreads();
  sum = red[4] + red[5] + red[6] + red[7];
  const float inv = 1.0f / sum;
#pragma unroll
  for (int i = 0; i < 4; i++) out[b * S + tid + i * 256] = e[i] * inv;
}

extern "C" void kernel_launch(void* const* d_in, const int* in_sizes, int n_in,
                              void* d_out, int out_size, void* d_ws, size_t ws_size,
                              hipStream_t stream) {
  const float* enc    = (const float*)d_in[0];  // (S,B,2H)
  const float* hidden = (const float*)d_in[1];  // (B,H)
  // d_in[2] = cell — unused by the reference
  const float* W_attn = (const float*)d_in[3];  // (H,3H)
  const float* b_attn = (const float*)d_in[4];  // (H)
  const float* v_w    = (const float*)d_in[5];  // (H)
  float* out = (float*)d_out;                   // (B,S)

  char* ws = (char*)d_ws;
  float* attn = (float*)ws;                                  // 128 KiB
  float* hp   = (float*)(ws + 131072);                       // 128 KiB
  u16* Web    = (u16*)(ws + 262144);                         // 4 MiB

  hipMemsetAsync(attn, 0, B * S * sizeof(float), stream);    // ws is 0xAA-poisoned each call
  conv_we_k<<<H, 256, 0, stream>>>(W_attn, Web);
  hproj_k<<<256, 256, 0, stream>>>(hidden, W_attn, b_attn, hp);
  gemm_fused_k<<<2048, 256, 0, stream>>>(enc, Web, hp, v_w, attn);
  softmax_k<<<B, 256, 0, stream>>>(attn, out);
}